// Round 9
// baseline (481.565 us; speedup 1.0000x reference)
//
#include <hip/hip_runtime.h>

#define NGRAPH 2048
#define EIDX_CAP 1024

typedef __attribute__((ext_vector_type(4))) float f32x4;
typedef __attribute__((ext_vector_type(8))) _Float16 h16x8;
typedef __attribute__((ext_vector_type(2))) _Float16 h16x2;

// ========== merged CSR build: histogram + scan (wave-parallel lookback) + fill ==========
// One persistent kernel, nchunk blocks (all co-resident: nchunk=391 << 2048 capacity).
// Grid barriers via counters in scanst[1000]/[1001] (zeroed by the preceding memset).
__global__ __launch_bounds__(256) void build_csr(
    const int* __restrict__ src, const int* __restrict__ dst,
    int* __restrict__ deg, int* __restrict__ rowstart, int* __restrict__ cursor,
    int* __restrict__ eidx, unsigned* __restrict__ scanst, int N, int E, int nchunk)
{
  __shared__ int tmp[256];
  __shared__ int sh_exc;
  int tid = threadIdx.x;
  int cb = blockIdx.x;
  int gsz = nchunk * 256;

  // ---- phase A: degree histogram (grid-stride) ----
  for (int e = cb * 256 + tid; e < E; e += gsz)
    atomicAdd(&deg[dst[e]], 1);

  // ---- grid barrier 1 ----
  __threadfence();
  __syncthreads();
  if (tid == 0) {
    atomicAdd(&scanst[1000], 1u);
    while (atomicAdd(&scanst[1000], 0u) < (unsigned)nchunk)
      __builtin_amdgcn_s_sleep(8);
  }
  __syncthreads();

  // ---- phase B: per-chunk scan + decoupled lookback (cb = blockIdx) ----
  int i = cb * 256 + tid;
  int v = (i < N) ? deg[i] : 0;
  tmp[tid] = v;
  __syncthreads();
#pragma unroll
  for (int off = 1; off < 256; off <<= 1) {
    int t = (tid >= off) ? tmp[tid - off] : 0;
    __syncthreads();
    tmp[tid] += t;
    __syncthreads();
  }
  int aggregate = tmp[255];
  const unsigned VMASK = (1u << 30) - 1u;

  if (cb == 0) {
    if (tid == 0) {
      atomicExch(&scanst[0], (2u << 30) | (unsigned)aggregate);
      sh_exc = 0;
    }
  } else {
    if (tid < 64) {
      if (tid == 0) atomicExch(&scanst[cb], (1u << 30) | (unsigned)aggregate);
      // wave-parallel lookback: 64 predecessors per hop
      int excv = 0;
      int base = cb - 1;
      for (;;) {
        int j = base - tid;
        unsigned s = 0u;
        if (j >= 0) {
          do { s = atomicAdd(&scanst[j], 0u); } while ((s >> 30) == 0u);
        }
        unsigned long long pm = __ballot(j >= 0 && (s >> 30) == 2u);
        if (pm) {
          int pl = __ffsll((long long)pm) - 1;
          if (tid <= pl && j >= 0) excv += (int)(s & VMASK);
          break;
        }
        if (j >= 0) excv += (int)(s & VMASK);
        base -= 64;
        if (base < 0) break;
      }
#pragma unroll
      for (int off = 32; off > 0; off >>= 1) excv += __shfl_xor(excv, off, 64);
      if (tid == 0) {
        sh_exc = excv;
        atomicExch(&scanst[cb], (2u << 30) | (unsigned)(excv + aggregate));
      }
    }
  }
  __syncthreads();
  int exc = sh_exc;
  if (i < N) {
    int rs = exc + tmp[tid] - v;
    rowstart[i] = rs;
    cursor[i] = rs;
  }
  if (cb == nchunk - 1 && tid == 0) rowstart[N] = E;

  // ---- grid barrier 2 (all cursor writes visible) ----
  __threadfence();
  __syncthreads();
  if (tid == 0) {
    atomicAdd(&scanst[1001], 1u);
    while (atomicAdd(&scanst[1001], 0u) < (unsigned)nchunk)
      __builtin_amdgcn_s_sleep(8);
  }
  __syncthreads();

  // ---- phase C: fill edge lists (grid-stride) ----
  for (int e = cb * 256 + tid; e < E; e += gsz) {
    int d = dst[e];
    int pos = atomicAdd(&cursor[d], 1);
    eidx[pos] = src[e];
  }
}

// ====== merged: weight repack(fp16 hi/lo) + x pad(fp16) + zero(bnstat)
//        + graph bounds + composed head weights Wc=jkw@c1w, bc=jkb@c1w ======
struct WPs {
  const float* w[5];
  _Float16* hi[5];
  _Float16* lo[5];
};
__global__ __launch_bounds__(256) void prep_hist(
    WPs p, const float* __restrict__ x, _Float16* __restrict__ x8h, int N,
    const int* __restrict__ batch, int* __restrict__ gstart,
    float* __restrict__ bnstat,
    const float* __restrict__ jkw, const float* __restrict__ jkb,
    const float* __restrict__ c1w, float* __restrict__ wc, float* __restrict__ bcv)
{
  int q = blockIdx.x * 256 + threadIdx.x;
  if (q < 5 * 16384) {
    int m = q >> 14;
    int j = q & 16383;
    int c = j >> 3, e = j & 7;
    int t = c >> 8, kc = (c >> 6) & 3, lane = c & 63;
    int n = t * 16 + (lane & 15);
    int k = kc * 32 + (lane >> 4) * 8 + e;
    float w = p.w[m][k * 128 + n];
    _Float16 h = (_Float16)w;
    p.hi[m][j] = h;
    p.lo[m][j] = (_Float16)(w - (float)h);
    return;
  }
  q -= 5 * 16384;
  if (q < N * 8) {
    int v = q >> 3, j = q & 7;
    x8h[q] = (_Float16)((j < 7) ? x[(long)v * 7 + j] : 0.f);
    return;
  }
  q -= N * 8;
  if (q < 256) { bnstat[q] = 0.f; return; }
  q -= 256;
  if (q < N) {
    int b = batch[q];
    int bp = (q > 0) ? batch[q - 1] : -1;
    for (int gg = bp + 1; gg <= b; ++gg) gstart[gg] = q;
    if (q == N - 1)
      for (int gg = b + 1; gg <= NGRAPH; ++gg) gstart[gg] = N;
    return;
  }
  q -= N;
  if (q < 384 * 128) {
    int k = q >> 7, n = q & 127;
    float acc = 0.f;
#pragma unroll 8
    for (int h = 0; h < 128; ++h)
      acc += jkw[k * 128 + h] * c1w[h * 128 + n];
    wc[q] = acc;
    return;
  }
  q -= 384 * 128;
  if (q < 128) {
    float acc = 0.f;
#pragma unroll 8
    for (int h = 0; h < 128; ++h)
      acc += jkb[h] * c1w[h * 128 + q];
    bcv[q] = acc;
  }
}

// ---- f16-MFMA GEMM pass: activations exact fp16 from LDS, weights fp16 hi+lo ----
__device__ inline void mfma_pass(
    const _Float16* __restrict__ zbuf,
    const _Float16* __restrict__ Whi, const _Float16* __restrict__ Wlo,
    int rw, int m16, int quad, int lane, f32x4 acc[8])
{
  int r = rw + m16;
  const _Float16* zrow = &zbuf[r * 128];
#pragma unroll
  for (int kc = 0; kc < 4; ++kc) {
    int cidx = kc * 4 + quad;
    h16x8 ah = *(const h16x8*)&zrow[((cidx + r) & 15) * 8];
#pragma unroll
    for (int t = 0; t < 8; ++t) {
      long cb = ((t * 4 + kc) * 64 + lane) * 8;
      h16x8 bh = *(const h16x8*)&Whi[cb];
      h16x8 bl = *(const h16x8*)&Wlo[cb];
      acc[t] = __builtin_amdgcn_mfma_f32_16x16x32_f16(ah, bh, acc[t], 0, 0, 0);
      acc[t] = __builtin_amdgcn_mfma_f32_16x16x32_f16(ah, bl, acc[t], 0, 0, 0);
    }
  }
}

// ================= fused GIN layer (layers 2,3): gather + MLP1 + MLP2 =================
__global__ __launch_bounds__(256, 5) void fused_gin(
    const _Float16* __restrict__ H, const int* __restrict__ rowstart,
    const int* __restrict__ eidx,
    const _Float16* __restrict__ W1hi, const _Float16* __restrict__ W1lo,
    const float* __restrict__ B1,
    const _Float16* __restrict__ W2hi, const _Float16* __restrict__ W2lo,
    const float* __restrict__ B2,
    _Float16* __restrict__ Out, int M)
{
  __shared__ _Float16 zbuf[64 * 128];   // 16 KB
  __shared__ int sh_rs[65];
  __shared__ int sh_ei[EIDX_CAP];       // 4 KB; block edge count ~Poisson(384), cap never hit
  int tid = threadIdx.x;
  int rbase = blockIdx.x * 64;

  if (tid < 65) {
    int v = rbase + tid;
    sh_rs[tid] = rowstart[(v < M) ? v : M];
  }
  __syncthreads();
  int e_begin = sh_rs[0];
  int cnt = sh_rs[64] - e_begin;
  if (cnt <= EIDX_CAP) {
    for (int i = tid; i < cnt; i += 256) sh_ei[i] = eidx[e_begin + i];
  }
  __syncthreads();

  {
    int sub = tid & 15;
    int ng = tid >> 4;
    const _Float16* Hc = H + sub * 8;
    if (cnt <= EIDX_CAP) {
#pragma unroll 1
      for (int it = 0; it < 4; ++it) {
        int r = it * 16 + ng;
        int v = rbase + r;
        int vc = (v < M) ? v : (M - 1);
        h16x8 sv = *(const h16x8*)&Hc[(long)vc * 128];
        float a0[8], a1[8];
#pragma unroll
        for (int j = 0; j < 8; ++j) { a0[j] = (float)sv[j]; a1[j] = 0.f; }
        int e = sh_rs[r] - e_begin;
        int e1 = sh_rs[r + 1] - e_begin;
#pragma unroll 1
        for (; e < e1; e += 8) {
          int last = e1 - 1;
          int s0 = sh_ei[e];
          int s1 = sh_ei[(e + 1 < e1) ? e + 1 : last];
          int s2 = sh_ei[(e + 2 < e1) ? e + 2 : last];
          int s3 = sh_ei[(e + 3 < e1) ? e + 3 : last];
          int s4 = sh_ei[(e + 4 < e1) ? e + 4 : last];
          int s5 = sh_ei[(e + 5 < e1) ? e + 5 : last];
          int s6 = sh_ei[(e + 6 < e1) ? e + 6 : last];
          int s7 = sh_ei[(e + 7 < e1) ? e + 7 : last];
          float m1 = (e + 1 < e1) ? 1.f : 0.f;
          float m2 = (e + 2 < e1) ? 1.f : 0.f;
          float m3 = (e + 3 < e1) ? 1.f : 0.f;
          float m4 = (e + 4 < e1) ? 1.f : 0.f;
          float m5 = (e + 5 < e1) ? 1.f : 0.f;
          float m6 = (e + 6 < e1) ? 1.f : 0.f;
          float m7 = (e + 7 < e1) ? 1.f : 0.f;
          h16x8 h0 = *(const h16x8*)&Hc[(long)s0 * 128];
          h16x8 h1 = *(const h16x8*)&Hc[(long)s1 * 128];
          h16x8 h2 = *(const h16x8*)&Hc[(long)s2 * 128];
          h16x8 h3 = *(const h16x8*)&Hc[(long)s3 * 128];
          h16x8 h4 = *(const h16x8*)&Hc[(long)s4 * 128];
          h16x8 h5 = *(const h16x8*)&Hc[(long)s5 * 128];
          h16x8 h6 = *(const h16x8*)&Hc[(long)s6 * 128];
          h16x8 h7 = *(const h16x8*)&Hc[(long)s7 * 128];
#pragma unroll
          for (int j = 0; j < 8; ++j) {
            a0[j] += (float)h0[j] + m2 * (float)h2[j] + m4 * (float)h4[j] + m6 * (float)h6[j];
            a1[j] += m1 * (float)h1[j] + m3 * (float)h3[j] + m5 * (float)h5[j] + m7 * (float)h7[j];
          }
        }
        h16x8 zo;
#pragma unroll
        for (int j = 0; j < 8; ++j) zo[j] = (_Float16)(a0[j] + a1[j]);
        *(h16x8*)&zbuf[r * 128 + ((sub + r) & 15) * 8] = zo;
      }
    } else {
      // fallback (block edge count exceeds LDS cap; statistically never for this input)
#pragma unroll 1
      for (int it = 0; it < 4; ++it) {
        int r = it * 16 + ng;
        int v = rbase + r;
        int vc = (v < M) ? v : (M - 1);
        h16x8 sv = *(const h16x8*)&Hc[(long)vc * 128];
        float a0[8], a1[8];
#pragma unroll
        for (int j = 0; j < 8; ++j) { a0[j] = (float)sv[j]; a1[j] = 0.f; }
        int e = sh_rs[r], e1 = sh_rs[r + 1];
        for (; e + 2 <= e1; e += 2) {
          int s0 = eidx[e], s1 = eidx[e + 1];
          h16x8 h0 = *(const h16x8*)&Hc[(long)s0 * 128];
          h16x8 h1 = *(const h16x8*)&Hc[(long)s1 * 128];
#pragma unroll
          for (int j = 0; j < 8; ++j) { a0[j] += (float)h0[j]; a1[j] += (float)h1[j]; }
        }
        if (e < e1) {
          int s = eidx[e];
          h16x8 h = *(const h16x8*)&Hc[(long)s * 128];
#pragma unroll
          for (int j = 0; j < 8; ++j) a1[j] += (float)h[j];
        }
        h16x8 zo;
#pragma unroll
        for (int j = 0; j < 8; ++j) zo[j] = (_Float16)(a0[j] + a1[j]);
        *(h16x8*)&zbuf[r * 128 + ((sub + r) & 15) * 8] = zo;
      }
    }
  }
  __syncthreads();

  int lane = tid & 63;
  int wv = tid >> 6;
  int m16 = lane & 15;
  int quad = lane >> 4;
  int rw = wv * 16;

  f32x4 acc[8];
#pragma unroll
  for (int t = 0; t < 8; ++t) acc[t] = (f32x4){0.f, 0.f, 0.f, 0.f};
  mfma_pass(zbuf, W1hi, W1lo, rw, m16, quad, lane, acc);

  float bias[8];
#pragma unroll
  for (int t = 0; t < 8; ++t) bias[t] = B1[t * 16 + m16];

  // each wave reads/writes ONLY its own 16-row zbuf slice in the MFMA phases -> no barriers
#pragma unroll
  for (int i = 0; i < 4; ++i) {
    int r = rw + quad * 4 + i;
#pragma unroll
    for (int t = 0; t < 8; ++t) {
      int col = t * 16 + m16;
      int cidx = col >> 3;
      zbuf[r * 128 + ((cidx + r) & 15) * 8 + (col & 7)] =
          (_Float16)fmaxf(acc[t][i] + bias[t], 0.f);
    }
  }

#pragma unroll
  for (int t = 0; t < 8; ++t) acc[t] = (f32x4){0.f, 0.f, 0.f, 0.f};
  mfma_pass(zbuf, W2hi, W2lo, rw, m16, quad, lane, acc);

#pragma unroll
  for (int t = 0; t < 8; ++t) bias[t] = B2[t * 16 + m16];

  // stage outputs in zbuf (own slice), then full-line coalesced 16B/lane stores
#pragma unroll
  for (int i = 0; i < 4; ++i) {
    int r = rw + quad * 4 + i;
#pragma unroll
    for (int t = 0; t < 8; ++t) {
      int col = t * 16 + m16;
      int cidx = col >> 3;
      zbuf[r * 128 + ((cidx + r) & 15) * 8 + (col & 7)] =
          (_Float16)fmaxf(acc[t][i] + bias[t], 0.f);
    }
  }
  {
    int rr2 = tid >> 2, c4 = tid & 3;
    int r = rbase + rr2;
    if (r < M) {
#pragma unroll
      for (int it = 0; it < 4; ++it) {
        int cidx = it * 4 + c4;
        h16x8 vv = *(const h16x8*)&zbuf[rr2 * 128 + ((cidx + rr2) & 15) * 8];
        *(h16x8*)&Out[(long)r * 128 + cidx * 8] = vv;
      }
    }
  }
}

// ================= fused layer 1: gather(x8h fp16) + K=7 GEMM + MFMA GEMM =================
__global__ __launch_bounds__(256, 8) void fused_l1(
    const _Float16* __restrict__ x8h, const int* __restrict__ rowstart,
    const int* __restrict__ eidx,
    const float* __restrict__ W1, const float* __restrict__ B1,
    const _Float16* __restrict__ W2hi, const _Float16* __restrict__ W2lo,
    const float* __restrict__ B2, _Float16* __restrict__ Out, int M)
{
  __shared__ _Float16 ybuf[64 * 128];
  __shared__ float z1s[64][8];
  int tid = threadIdx.x;
  int rbase = blockIdx.x * 64;

  {
    int node = tid >> 2, sub = tid & 3;
    int v = rbase + node;
    int vc = (v < M) ? v : (M - 1);
    float a[8];
    if (sub == 0) {
      h16x8 sv = *(const h16x8*)&x8h[(long)vc * 8];
#pragma unroll
      for (int j = 0; j < 8; ++j) a[j] = (float)sv[j];
    } else {
#pragma unroll
      for (int j = 0; j < 8; ++j) a[j] = 0.f;
    }
    int e0 = rowstart[vc], e1 = rowstart[vc + 1];
    int e = e0 + sub;
    for (; e + 4 < e1; e += 8) {
      int s0 = eidx[e], s1 = eidx[e + 4];
      h16x8 h0 = *(const h16x8*)&x8h[(long)s0 * 8];
      h16x8 h1 = *(const h16x8*)&x8h[(long)s1 * 8];
#pragma unroll
      for (int j = 0; j < 8; ++j) a[j] += (float)h0[j] + (float)h1[j];
    }
    if (e < e1) {
      int s = eidx[e];
      h16x8 h = *(const h16x8*)&x8h[(long)s * 8];
#pragma unroll
      for (int j = 0; j < 8; ++j) a[j] += (float)h[j];
    }
#pragma unroll
    for (int j = 0; j < 8; ++j) {
      a[j] += __shfl_xor(a[j], 1, 64);
      a[j] += __shfl_xor(a[j], 2, 64);
    }
    if (sub == 0) {
#pragma unroll
      for (int j = 0; j < 8; ++j) z1s[node][j] = a[j];
    }
  }
  __syncthreads();

  {
    int c = tid & 127;
    int cidx = c >> 3, celt = c & 7;
    int rh0 = (tid >> 7) * 32;
    float w1r[7];
#pragma unroll
    for (int k = 0; k < 7; ++k) w1r[k] = W1[k * 128 + c];
    float b1 = B1[c];
#pragma unroll 4
    for (int rr = 0; rr < 32; ++rr) {
      int r = rh0 + rr;
      const float* zp = z1s[r];
      float a = b1;
#pragma unroll
      for (int k = 0; k < 7; ++k) a += zp[k] * w1r[k];
      ybuf[r * 128 + ((cidx + r) & 15) * 8 + celt] = (_Float16)fmaxf(a, 0.f);
    }
  }
  __syncthreads();

  int lane = tid & 63;
  int wv = tid >> 6;
  int m16 = lane & 15;
  int quad = lane >> 4;
  int rw = wv * 16;

  f32x4 acc[8];
#pragma unroll
  for (int t = 0; t < 8; ++t) acc[t] = (f32x4){0.f, 0.f, 0.f, 0.f};
  mfma_pass(ybuf, W2hi, W2lo, rw, m16, quad, lane, acc);

  float bias[8];
#pragma unroll
  for (int t = 0; t < 8; ++t) bias[t] = B2[t * 16 + m16];

  // stage outputs in ybuf (own 16-row slice, no barrier needed), coalesced store
#pragma unroll
  for (int i = 0; i < 4; ++i) {
    int r = rw + quad * 4 + i;
#pragma unroll
    for (int t = 0; t < 8; ++t) {
      int col = t * 16 + m16;
      int cidx = col >> 3;
      ybuf[r * 128 + ((cidx + r) & 15) * 8 + (col & 7)] =
          (_Float16)fmaxf(acc[t][i] + bias[t], 0.f);
    }
  }
  {
    int rr2 = tid >> 2, c4 = tid & 3;
    int r = rbase + rr2;
    if (r < M) {
#pragma unroll
      for (int it = 0; it < 4; ++it) {
        int cidx = it * 4 + c4;
        h16x8 vv = *(const h16x8*)&ybuf[rr2 * 128 + ((cidx + rr2) & 15) * 8];
        *(h16x8*)&Out[(long)r * 128 + cidx * 8] = vv;
      }
    }
  }
}

// ================= pooling v2: wave-per-row 16B loads, LDS cross-wave reduce =================
__global__ __launch_bounds__(256) void pool_direct(
    const _Float16* __restrict__ H1, const _Float16* __restrict__ H2,
    const _Float16* __restrict__ H3, const int* __restrict__ gstart,
    float* __restrict__ P)
{
  __shared__ float red[3 * 16 * 8 * 4];   // [tbl][chunk][elt][wave] = 6 KB
  int g = blockIdx.x;
  int s = gstart[g], e = gstart[g + 1];
  int tid = threadIdx.x;
  int wv = tid >> 6, lane = tid & 63;
  int tbl = lane >> 4;
  int ch = lane & 15;
  float a[8];
#pragma unroll
  for (int j = 0; j < 8; ++j) a[j] = 0.f;
  if (tbl < 3) {
    const _Float16* A = (tbl == 0) ? H1 : ((tbl == 1) ? H2 : H3);
    const _Float16* Ac = A + ch * 8;
    for (int r = s + wv; r < e; r += 4) {
      h16x8 v = *(const h16x8*)&Ac[(long)r * 128];
#pragma unroll
      for (int j = 0; j < 8; ++j) a[j] += (float)v[j];
    }
#pragma unroll
    for (int j = 0; j < 8; ++j) red[((tbl * 16 + ch) * 8 + j) * 4 + wv] = a[j];
  }
  __syncthreads();
  for (int t = tid; t < 384; t += 256) {
    float4 rv = *(const float4*)&red[t * 4];
    P[(long)g * 384 + t] = rv.x + rv.y + rv.z + rv.w;
  }
}

// ======== fused head GEMM: zc = P @ Wc + cnt*bc + c1b, with BN stat atomics ========
__global__ __launch_bounds__(256) void jk_bn(
    const float* __restrict__ P, const int* __restrict__ gstart,
    const float* __restrict__ Wc, const float* __restrict__ bc,
    const float* __restrict__ c1b,
    float* __restrict__ zc, float* __restrict__ bnstat)
{
  __shared__ float pl[8 * 384];   // 12 KB
  __shared__ float red[512];
  int tid = threadIdx.x, blk = blockIdx.x;
  int r0 = blk * 8;
  for (int o = tid; o < 8 * 384; o += 256)
    pl[o] = P[(long)r0 * 384 + o];
  __syncthreads();
  int col = tid & 127, rg = tid >> 7;
  float acc[4];
  float b0 = bc[col], b1 = c1b[col];
#pragma unroll
  for (int i = 0; i < 4; ++i) {
    int row = r0 + rg + 2 * i;
    float cntv = (float)(gstart[row + 1] - gstart[row]);
    acc[i] = cntv * b0 + b1;
  }
#pragma unroll 4
  for (int k = 0; k < 384; ++k) {
    float w = Wc[k * 128 + col];
#pragma unroll
    for (int i = 0; i < 4; ++i)
      acc[i] += pl[(rg + 2 * i) * 384 + k] * w;
  }
  float s = 0.f, s2 = 0.f;
#pragma unroll
  for (int i = 0; i < 4; ++i) {
    int row = r0 + rg + 2 * i;
    zc[(long)row * 128 + col] = acc[i];
    s += acc[i]; s2 += acc[i] * acc[i];
  }
  red[tid] = s; red[256 + tid] = s2;
  __syncthreads();
  if (tid < 128) {
    atomicAdd(&bnstat[tid], red[tid] + red[tid + 128]);
    atomicAdd(&bnstat[128 + tid], red[256 + tid] + red[256 + tid + 128]);
  }
}

// ================= BN apply + relu + final [128x2] matmul (64 graphs/block) =================
__global__ __launch_bounds__(256) void bn_final(
    const float* __restrict__ ZC, const float* __restrict__ bnstat,
    const float* __restrict__ gma, const float* __restrict__ bta,
    const float* __restrict__ W2, const float* __restrict__ B2, float* __restrict__ out)
{
  __shared__ float scl[128], shf[128];
  __shared__ float zl[64 * 132];   // stride 132 -> conflict-free reads
  int tid = threadIdx.x;
  if (tid < 128) {
    float mu = bnstat[tid] * (1.f / NGRAPH);
    float var = bnstat[128 + tid] * (1.f / NGRAPH) - mu * mu;
    float rs = rsqrtf(var + 1e-5f);
    float sc = gma[tid] * rs;
    scl[tid] = sc;
    shf[tid] = bta[tid] - mu * sc;
  }
  int g0 = blockIdx.x * 64;
  for (int i = tid; i < 64 * 128; i += 256) {
    int r = i >> 7, c = i & 127;
    zl[r * 132 + c] = ZC[(long)(g0 + r) * 128 + c];
  }
  __syncthreads();
  int q = tid >> 2, sub = tid & 3;
  int g = g0 + q;
  float a0 = 0.f, a1 = 0.f;
#pragma unroll 8
  for (int hh = 0; hh < 32; ++hh) {
    int h = sub + hh * 4;
    float zn = zl[q * 132 + h] * scl[h] + shf[h];
    zn = fmaxf(zn, 0.f);
    a0 += zn * W2[2 * h];
    a1 += zn * W2[2 * h + 1];
  }
  a0 += __shfl_xor(a0, 1, 64); a0 += __shfl_xor(a0, 2, 64);
  a1 += __shfl_xor(a1, 1, 64); a1 += __shfl_xor(a1, 2, 64);
  if (sub == 0) {
    out[2 * g] = a0 + B2[0];
    out[2 * g + 1] = a1 + B2[1];
  }
}

extern "C" void kernel_launch(void* const* d_in, const int* in_sizes, int n_in,
                              void* d_out, int out_size, void* d_ws, size_t ws_size,
                              hipStream_t stream)
{
  const float* x    = (const float*)d_in[0];
  const int*   ei   = (const int*)d_in[1];
  const int*   batch = (const int*)d_in[3];
  const float* g1w1 = (const float*)d_in[4];  const float* g1b1 = (const float*)d_in[5];
  const float* g1w2 = (const float*)d_in[6];  const float* g1b2 = (const float*)d_in[7];
  const float* g2w1 = (const float*)d_in[8];  const float* g2b1 = (const float*)d_in[9];
  const float* g2w2 = (const float*)d_in[10]; const float* g2b2 = (const float*)d_in[11];
  const float* g3w1 = (const float*)d_in[12]; const float* g3b1 = (const float*)d_in[13];
  const float* g3w2 = (const float*)d_in[14]; const float* g3b2 = (const float*)d_in[15];
  const float* jkw  = (const float*)d_in[16]; const float* jkb  = (const float*)d_in[17];
  const float* c1w  = (const float*)d_in[18]; const float* c1b  = (const float*)d_in[19];
  const float* bng  = (const float*)d_in[20]; const float* bnb  = (const float*)d_in[21];
  const float* c2w  = (const float*)d_in[22]; const float* c2b  = (const float*)d_in[23];

  const int N = in_sizes[3];
  const int E = in_sizes[1] / 2;
  const int* src = ei;
  const int* dst = ei + E;

  char* w = (char*)d_ws;
  auto alloc = [&](size_t bytes) {
    char* p = w;
    w += (bytes + 255) & ~(size_t)255;
    return p;
  };
  _Float16* hA = (_Float16*)alloc((size_t)N * 128 * 2);   // layer-3 out
  _Float16* hB = (_Float16*)alloc((size_t)N * 128 * 2);   // layer-2 out
  _Float16* hC = (_Float16*)alloc((size_t)N * 128 * 2);   // layer-1 out
  _Float16* x8h = (_Float16*)alloc((size_t)N * 8 * 2);
  float* P       = (float*)alloc((size_t)NGRAPH * 384 * 4);
  float* bnstat  = (float*)alloc(256 * 4);
  float* zc   = (float*)alloc((size_t)NGRAPH * 128 * 4);
  float* wc   = (float*)alloc((size_t)384 * 128 * 4);
  float* bcv  = (float*)alloc((size_t)128 * 4);
  // deg, scanst contiguous -> one memset
  int* deg      = (int*)alloc((size_t)N * 4);
  unsigned* scanst = (unsigned*)alloc((size_t)1024 * 4);
  int* cursor   = (int*)alloc((size_t)N * 4);
  int* rowstart = (int*)alloc((size_t)(N + 1) * 4);
  int* eidx     = (int*)alloc((size_t)E * 4);
  int* gstart   = (int*)alloc((size_t)(NGRAPH + 1) * 4);
  _Float16* wtbuf = (_Float16*)alloc((size_t)5 * 2 * 16384 * 2);

  _Float16* WThi[5];
  _Float16* WTlo[5];
  for (int m = 0; m < 5; ++m) {
    WThi[m] = wtbuf + (size_t)m * 2 * 16384;
    WTlo[m] = WThi[m] + 16384;
  }

  const int nchunk = (N + 255) / 256;

  // ---- memset deg+scanst (contiguous allocs incl. padding) ----
  hipMemsetAsync(deg, 0, (size_t)((char*)(scanst + 1024) - (char*)deg), stream);

  // ---- merged CSR build: histogram + scan + fill, one persistent kernel ----
  build_csr<<<nchunk, 256, 0, stream>>>(src, dst, deg, rowstart, cursor, eidx,
                                        scanst, N, E, nchunk);

  // ---- merged prep: weight repack + x pad + zero(bnstat) + graph bounds + Wc/bc ----
  {
    WPs p;
    p.w[0] = g1w2; p.w[1] = g2w1; p.w[2] = g2w2; p.w[3] = g3w1; p.w[4] = g3w2;
    for (int m = 0; m < 5; ++m) { p.hi[m] = WThi[m]; p.lo[m] = WTlo[m]; }
    int total = 5 * 16384 + N * 8 + 256 + N + 384 * 128 + 128;
    prep_hist<<<(total + 255) / 256, 256, 0, stream>>>(p, x, x8h, N,
                                                       batch, gstart, bnstat,
                                                       jkw, jkb, c1w, wc, bcv);
  }

  const int fBlocks = (N + 63) / 64;

  // ---- layers (re-fused; f16-MFMA weights) ----
  fused_l1<<<fBlocks, 256, 0, stream>>>(x8h, rowstart, eidx, g1w1, g1b1,
      WThi[0], WTlo[0], g1b2, hC, N);
  fused_gin<<<fBlocks, 256, 0, stream>>>(hC, rowstart, eidx,
      WThi[1], WTlo[1], g2b1, WThi[2], WTlo[2], g2b2, hB, N);
  fused_gin<<<fBlocks, 256, 0, stream>>>(hB, rowstart, eidx,
      WThi[3], WTlo[3], g3b1, WThi[4], WTlo[4], g3b2, hA, N);

  // ---- pooling v2: one block per graph, 16B loads, no atomics ----
  pool_direct<<<NGRAPH, 256, 0, stream>>>(hC, hB, hA, gstart, P);

  // ---- fused head: zc = P@Wc + cnt*bc + c1b (+BN stats), then BN+final ----
  jk_bn<<<NGRAPH / 8, 256, 0, stream>>>(P, gstart, wc, bcv, c1b, zc, bnstat);
  bn_final<<<NGRAPH / 64, 256, 0, stream>>>(zc, bnstat, bng, bnb, c2w, c2b, (float*)d_out);
}

// Round 10
// 368.484 us; speedup vs baseline: 1.3069x; 1.3069x over previous
//
#include <hip/hip_runtime.h>

#define NGRAPH 2048
#define EIDX_CAP 1024

typedef __attribute__((ext_vector_type(4))) float f32x4;
typedef __attribute__((ext_vector_type(8))) _Float16 h16x8;
typedef __attribute__((ext_vector_type(2))) _Float16 h16x2;

// ========== single-pass scan (ticket + decoupled lookback, WAVE-PARALLEL lookback) ==========
__global__ __launch_bounds__(256) void scan_onepass(
    const int* __restrict__ deg, int* __restrict__ rowstart,
    unsigned* __restrict__ scanst, int N, int E, int nchunk)
{
  __shared__ int tmp[256];
  __shared__ int sh_chunk;
  __shared__ int sh_exc;
  int tid = threadIdx.x;
  if (tid == 0) sh_chunk = (int)atomicAdd(&scanst[nchunk], 1u);
  __syncthreads();
  int cb = sh_chunk;
  int i = cb * 256 + tid;
  int v = (i < N) ? deg[i] : 0;
  tmp[tid] = v;
  __syncthreads();
#pragma unroll
  for (int off = 1; off < 256; off <<= 1) {
    int t = (tid >= off) ? tmp[tid - off] : 0;
    __syncthreads();
    tmp[tid] += t;
    __syncthreads();
  }
  int aggregate = tmp[255];
  const unsigned VMASK = (1u << 30) - 1u;

  if (cb == 0) {
    if (tid == 0) {
      atomicExch(&scanst[0], (2u << 30) | (unsigned)aggregate);
      sh_exc = 0;
    }
  } else {
    if (tid < 64) {
      if (tid == 0) atomicExch(&scanst[cb], (1u << 30) | (unsigned)aggregate);
      // wave-parallel decoupled lookback: 64 predecessors per hop
      int excv = 0;
      int base = cb - 1;
      for (;;) {
        int j = base - tid;
        unsigned s = 0u;
        if (j >= 0) {
          do { s = atomicAdd(&scanst[j], 0u); } while ((s >> 30) == 0u);
        }
        unsigned long long pm = __ballot(j >= 0 && (s >> 30) == 2u);
        if (pm) {
          int pl = __ffsll((long long)pm) - 1;
          if (tid <= pl && j >= 0) excv += (int)(s & VMASK);
          break;
        }
        if (j >= 0) excv += (int)(s & VMASK);
        base -= 64;
        if (base < 0) break;
      }
#pragma unroll
      for (int off = 32; off > 0; off >>= 1) excv += __shfl_xor(excv, off, 64);
      if (tid == 0) {
        sh_exc = excv;
        atomicExch(&scanst[cb], (2u << 30) | (unsigned)(excv + aggregate));
      }
    }
  }
  __syncthreads();
  int exc = sh_exc;
  if (i < N) rowstart[i] = exc + tmp[tid] - v;
  if (cb == nchunk - 1 && tid == 0) rowstart[N] = E;
}

// ---- atomic-free fill: position = rowstart[dst] + rank (rank captured in histogram) ----
__global__ __launch_bounds__(256) void fill_eidx(
    const int* __restrict__ src, const int* __restrict__ dst,
    const int* __restrict__ rank, const int* __restrict__ rowstart,
    int* __restrict__ eidx, int E)
{
  int e = blockIdx.x * 256 + threadIdx.x;
  if (e >= E) return;
  int d = dst[e];
  eidx[rowstart[d] + rank[e]] = src[e];
}

// ====== merged: degree hist (captures per-edge rank) + weight repack(fp16 hi/lo)
//        + x pad(fp16) + zero(bnstat) + graph bounds + composed Wc=jkw@c1w, bc=jkb@c1w ======
struct WPs {
  const float* w[5];
  _Float16* hi[5];
  _Float16* lo[5];
};
__global__ __launch_bounds__(256) void prep_hist(
    WPs p, const float* __restrict__ x, _Float16* __restrict__ x8h, int N,
    const int* __restrict__ dst, int* __restrict__ deg, int* __restrict__ rank, int E,
    const int* __restrict__ batch, int* __restrict__ gstart,
    float* __restrict__ bnstat,
    const float* __restrict__ jkw, const float* __restrict__ jkb,
    const float* __restrict__ c1w, float* __restrict__ wc, float* __restrict__ bcv)
{
  int g = blockIdx.x * 256 + threadIdx.x;
  if (g < E) {
    rank[g] = atomicAdd(&deg[dst[g]], 1);
    return;
  }
  int q = g - E;
  if (q < 5 * 16384) {
    int m = q >> 14;
    int j = q & 16383;
    int c = j >> 3, e = j & 7;
    int t = c >> 8, kc = (c >> 6) & 3, lane = c & 63;
    int n = t * 16 + (lane & 15);
    int k = kc * 32 + (lane >> 4) * 8 + e;
    float w = p.w[m][k * 128 + n];
    _Float16 h = (_Float16)w;
    p.hi[m][j] = h;
    p.lo[m][j] = (_Float16)(w - (float)h);
    return;
  }
  q -= 5 * 16384;
  if (q < N * 8) {
    int v = q >> 3, j = q & 7;
    x8h[q] = (_Float16)((j < 7) ? x[(long)v * 7 + j] : 0.f);
    return;
  }
  q -= N * 8;
  if (q < 256) { bnstat[q] = 0.f; return; }
  q -= 256;
  if (q < N) {
    int b = batch[q];
    int bp = (q > 0) ? batch[q - 1] : -1;
    for (int gg = bp + 1; gg <= b; ++gg) gstart[gg] = q;
    if (q == N - 1)
      for (int gg = b + 1; gg <= NGRAPH; ++gg) gstart[gg] = N;
    return;
  }
  q -= N;
  if (q < 384 * 128) {
    int k = q >> 7, n = q & 127;
    float acc = 0.f;
#pragma unroll 8
    for (int h = 0; h < 128; ++h)
      acc += jkw[k * 128 + h] * c1w[h * 128 + n];
    wc[q] = acc;
    return;
  }
  q -= 384 * 128;
  if (q < 128) {
    float acc = 0.f;
#pragma unroll 8
    for (int h = 0; h < 128; ++h)
      acc += jkb[h] * c1w[h * 128 + q];
    bcv[q] = acc;
  }
}

// ---- f16-MFMA GEMM pass: activations exact fp16 from LDS, weights fp16 hi+lo ----
__device__ inline void mfma_pass(
    const _Float16* __restrict__ zbuf,
    const _Float16* __restrict__ Whi, const _Float16* __restrict__ Wlo,
    int rw, int m16, int quad, int lane, f32x4 acc[8])
{
  int r = rw + m16;
  const _Float16* zrow = &zbuf[r * 128];
#pragma unroll
  for (int kc = 0; kc < 4; ++kc) {
    int cidx = kc * 4 + quad;
    h16x8 ah = *(const h16x8*)&zrow[((cidx + r) & 15) * 8];
#pragma unroll
    for (int t = 0; t < 8; ++t) {
      long cb = ((t * 4 + kc) * 64 + lane) * 8;
      h16x8 bh = *(const h16x8*)&Whi[cb];
      h16x8 bl = *(const h16x8*)&Wlo[cb];
      acc[t] = __builtin_amdgcn_mfma_f32_16x16x32_f16(ah, bh, acc[t], 0, 0, 0);
      acc[t] = __builtin_amdgcn_mfma_f32_16x16x32_f16(ah, bl, acc[t], 0, 0, 0);
    }
  }
}

// ================= fused GIN layer (layers 2,3): gather + MLP1 + MLP2 =================
__global__ __launch_bounds__(256, 5) void fused_gin(
    const _Float16* __restrict__ H, const int* __restrict__ rowstart,
    const int* __restrict__ eidx,
    const _Float16* __restrict__ W1hi, const _Float16* __restrict__ W1lo,
    const float* __restrict__ B1,
    const _Float16* __restrict__ W2hi, const _Float16* __restrict__ W2lo,
    const float* __restrict__ B2,
    _Float16* __restrict__ Out, int M)
{
  __shared__ _Float16 zbuf[64 * 128];   // 16 KB
  __shared__ int sh_rs[65];
  __shared__ int sh_ei[EIDX_CAP];       // 4 KB; block edge count ~Poisson(384), cap never hit
  int tid = threadIdx.x;
  int rbase = blockIdx.x * 64;

  if (tid < 65) {
    int v = rbase + tid;
    sh_rs[tid] = rowstart[(v < M) ? v : M];
  }
  __syncthreads();
  int e_begin = sh_rs[0];
  int cnt = sh_rs[64] - e_begin;
  if (cnt <= EIDX_CAP) {
    for (int i = tid; i < cnt; i += 256) sh_ei[i] = eidx[e_begin + i];
  }
  __syncthreads();

  {
    int sub = tid & 15;
    int ng = tid >> 4;
    const _Float16* Hc = H + sub * 8;
    if (cnt <= EIDX_CAP) {
#pragma unroll 1
      for (int it = 0; it < 4; ++it) {
        int r = it * 16 + ng;
        int v = rbase + r;
        int vc = (v < M) ? v : (M - 1);
        h16x8 sv = *(const h16x8*)&Hc[(long)vc * 128];
        float a0[8], a1[8];
#pragma unroll
        for (int j = 0; j < 8; ++j) { a0[j] = (float)sv[j]; a1[j] = 0.f; }
        int e = sh_rs[r] - e_begin;
        int e1 = sh_rs[r + 1] - e_begin;
#pragma unroll 1
        for (; e < e1; e += 8) {
          int last = e1 - 1;
          int s0 = sh_ei[e];
          int s1 = sh_ei[(e + 1 < e1) ? e + 1 : last];
          int s2 = sh_ei[(e + 2 < e1) ? e + 2 : last];
          int s3 = sh_ei[(e + 3 < e1) ? e + 3 : last];
          int s4 = sh_ei[(e + 4 < e1) ? e + 4 : last];
          int s5 = sh_ei[(e + 5 < e1) ? e + 5 : last];
          int s6 = sh_ei[(e + 6 < e1) ? e + 6 : last];
          int s7 = sh_ei[(e + 7 < e1) ? e + 7 : last];
          float m1 = (e + 1 < e1) ? 1.f : 0.f;
          float m2 = (e + 2 < e1) ? 1.f : 0.f;
          float m3 = (e + 3 < e1) ? 1.f : 0.f;
          float m4 = (e + 4 < e1) ? 1.f : 0.f;
          float m5 = (e + 5 < e1) ? 1.f : 0.f;
          float m6 = (e + 6 < e1) ? 1.f : 0.f;
          float m7 = (e + 7 < e1) ? 1.f : 0.f;
          h16x8 h0 = *(const h16x8*)&Hc[(long)s0 * 128];
          h16x8 h1 = *(const h16x8*)&Hc[(long)s1 * 128];
          h16x8 h2 = *(const h16x8*)&Hc[(long)s2 * 128];
          h16x8 h3 = *(const h16x8*)&Hc[(long)s3 * 128];
          h16x8 h4 = *(const h16x8*)&Hc[(long)s4 * 128];
          h16x8 h5 = *(const h16x8*)&Hc[(long)s5 * 128];
          h16x8 h6 = *(const h16x8*)&Hc[(long)s6 * 128];
          h16x8 h7 = *(const h16x8*)&Hc[(long)s7 * 128];
#pragma unroll
          for (int j = 0; j < 8; ++j) {
            a0[j] += (float)h0[j] + m2 * (float)h2[j] + m4 * (float)h4[j] + m6 * (float)h6[j];
            a1[j] += m1 * (float)h1[j] + m3 * (float)h3[j] + m5 * (float)h5[j] + m7 * (float)h7[j];
          }
        }
        h16x8 zo;
#pragma unroll
        for (int j = 0; j < 8; ++j) zo[j] = (_Float16)(a0[j] + a1[j]);
        *(h16x8*)&zbuf[r * 128 + ((sub + r) & 15) * 8] = zo;
      }
    } else {
      // fallback (block edge count exceeds LDS cap; statistically never for this input)
#pragma unroll 1
      for (int it = 0; it < 4; ++it) {
        int r = it * 16 + ng;
        int v = rbase + r;
        int vc = (v < M) ? v : (M - 1);
        h16x8 sv = *(const h16x8*)&Hc[(long)vc * 128];
        float a0[8], a1[8];
#pragma unroll
        for (int j = 0; j < 8; ++j) { a0[j] = (float)sv[j]; a1[j] = 0.f; }
        int e = sh_rs[r], e1 = sh_rs[r + 1];
        for (; e + 2 <= e1; e += 2) {
          int s0 = eidx[e], s1 = eidx[e + 1];
          h16x8 h0 = *(const h16x8*)&Hc[(long)s0 * 128];
          h16x8 h1 = *(const h16x8*)&Hc[(long)s1 * 128];
#pragma unroll
          for (int j = 0; j < 8; ++j) { a0[j] += (float)h0[j]; a1[j] += (float)h1[j]; }
        }
        if (e < e1) {
          int s = eidx[e];
          h16x8 h = *(const h16x8*)&Hc[(long)s * 128];
#pragma unroll
          for (int j = 0; j < 8; ++j) a1[j] += (float)h[j];
        }
        h16x8 zo;
#pragma unroll
        for (int j = 0; j < 8; ++j) zo[j] = (_Float16)(a0[j] + a1[j]);
        *(h16x8*)&zbuf[r * 128 + ((sub + r) & 15) * 8] = zo;
      }
    }
  }
  __syncthreads();

  int lane = tid & 63;
  int wv = tid >> 6;
  int m16 = lane & 15;
  int quad = lane >> 4;
  int rw = wv * 16;

  f32x4 acc[8];
#pragma unroll
  for (int t = 0; t < 8; ++t) acc[t] = (f32x4){0.f, 0.f, 0.f, 0.f};
  mfma_pass(zbuf, W1hi, W1lo, rw, m16, quad, lane, acc);

  float bias[8];
#pragma unroll
  for (int t = 0; t < 8; ++t) bias[t] = B1[t * 16 + m16];

  // each wave reads/writes ONLY its own 16-row zbuf slice in the MFMA phases -> no barriers
#pragma unroll
  for (int i = 0; i < 4; ++i) {
    int r = rw + quad * 4 + i;
#pragma unroll
    for (int t = 0; t < 8; ++t) {
      int col = t * 16 + m16;
      int cidx = col >> 3;
      zbuf[r * 128 + ((cidx + r) & 15) * 8 + (col & 7)] =
          (_Float16)fmaxf(acc[t][i] + bias[t], 0.f);
    }
  }

#pragma unroll
  for (int t = 0; t < 8; ++t) acc[t] = (f32x4){0.f, 0.f, 0.f, 0.f};
  mfma_pass(zbuf, W2hi, W2lo, rw, m16, quad, lane, acc);

#pragma unroll
  for (int t = 0; t < 8; ++t) bias[t] = B2[t * 16 + m16];

  // stage outputs in zbuf (own slice), then full-line coalesced 16B/lane stores
#pragma unroll
  for (int i = 0; i < 4; ++i) {
    int r = rw + quad * 4 + i;
#pragma unroll
    for (int t = 0; t < 8; ++t) {
      int col = t * 16 + m16;
      int cidx = col >> 3;
      zbuf[r * 128 + ((cidx + r) & 15) * 8 + (col & 7)] =
          (_Float16)fmaxf(acc[t][i] + bias[t], 0.f);
    }
  }
  {
    int rr2 = tid >> 2, c4 = tid & 3;
    int r = rbase + rr2;
    if (r < M) {
#pragma unroll
      for (int it = 0; it < 4; ++it) {
        int cidx = it * 4 + c4;
        h16x8 vv = *(const h16x8*)&zbuf[rr2 * 128 + ((cidx + rr2) & 15) * 8];
        *(h16x8*)&Out[(long)r * 128 + cidx * 8] = vv;
      }
    }
  }
}

// ================= fused layer 1: gather(x8h fp16) + K=7 GEMM + MFMA GEMM =================
__global__ __launch_bounds__(256, 8) void fused_l1(
    const _Float16* __restrict__ x8h, const int* __restrict__ rowstart,
    const int* __restrict__ eidx,
    const float* __restrict__ W1, const float* __restrict__ B1,
    const _Float16* __restrict__ W2hi, const _Float16* __restrict__ W2lo,
    const float* __restrict__ B2, _Float16* __restrict__ Out, int M)
{
  __shared__ _Float16 ybuf[64 * 128];
  __shared__ float z1s[64][8];
  int tid = threadIdx.x;
  int rbase = blockIdx.x * 64;

  {
    int node = tid >> 2, sub = tid & 3;
    int v = rbase + node;
    int vc = (v < M) ? v : (M - 1);
    float a[8];
    if (sub == 0) {
      h16x8 sv = *(const h16x8*)&x8h[(long)vc * 8];
#pragma unroll
      for (int j = 0; j < 8; ++j) a[j] = (float)sv[j];
    } else {
#pragma unroll
      for (int j = 0; j < 8; ++j) a[j] = 0.f;
    }
    int e0 = rowstart[vc], e1 = rowstart[vc + 1];
    int e = e0 + sub;
    for (; e + 4 < e1; e += 8) {
      int s0 = eidx[e], s1 = eidx[e + 4];
      h16x8 h0 = *(const h16x8*)&x8h[(long)s0 * 8];
      h16x8 h1 = *(const h16x8*)&x8h[(long)s1 * 8];
#pragma unroll
      for (int j = 0; j < 8; ++j) a[j] += (float)h0[j] + (float)h1[j];
    }
    if (e < e1) {
      int s = eidx[e];
      h16x8 h = *(const h16x8*)&x8h[(long)s * 8];
#pragma unroll
      for (int j = 0; j < 8; ++j) a[j] += (float)h[j];
    }
#pragma unroll
    for (int j = 0; j < 8; ++j) {
      a[j] += __shfl_xor(a[j], 1, 64);
      a[j] += __shfl_xor(a[j], 2, 64);
    }
    if (sub == 0) {
#pragma unroll
      for (int j = 0; j < 8; ++j) z1s[node][j] = a[j];
    }
  }
  __syncthreads();

  {
    int c = tid & 127;
    int cidx = c >> 3, celt = c & 7;
    int rh0 = (tid >> 7) * 32;
    float w1r[7];
#pragma unroll
    for (int k = 0; k < 7; ++k) w1r[k] = W1[k * 128 + c];
    float b1 = B1[c];
#pragma unroll 4
    for (int rr = 0; rr < 32; ++rr) {
      int r = rh0 + rr;
      const float* zp = z1s[r];
      float a = b1;
#pragma unroll
      for (int k = 0; k < 7; ++k) a += zp[k] * w1r[k];
      ybuf[r * 128 + ((cidx + r) & 15) * 8 + celt] = (_Float16)fmaxf(a, 0.f);
    }
  }
  __syncthreads();

  int lane = tid & 63;
  int wv = tid >> 6;
  int m16 = lane & 15;
  int quad = lane >> 4;
  int rw = wv * 16;

  f32x4 acc[8];
#pragma unroll
  for (int t = 0; t < 8; ++t) acc[t] = (f32x4){0.f, 0.f, 0.f, 0.f};
  mfma_pass(ybuf, W2hi, W2lo, rw, m16, quad, lane, acc);

  float bias[8];
#pragma unroll
  for (int t = 0; t < 8; ++t) bias[t] = B2[t * 16 + m16];

  // stage outputs in ybuf (own 16-row slice, no barrier needed), coalesced store
#pragma unroll
  for (int i = 0; i < 4; ++i) {
    int r = rw + quad * 4 + i;
#pragma unroll
    for (int t = 0; t < 8; ++t) {
      int col = t * 16 + m16;
      int cidx = col >> 3;
      ybuf[r * 128 + ((cidx + r) & 15) * 8 + (col & 7)] =
          (_Float16)fmaxf(acc[t][i] + bias[t], 0.f);
    }
  }
  {
    int rr2 = tid >> 2, c4 = tid & 3;
    int r = rbase + rr2;
    if (r < M) {
#pragma unroll
      for (int it = 0; it < 4; ++it) {
        int cidx = it * 4 + c4;
        h16x8 vv = *(const h16x8*)&ybuf[rr2 * 128 + ((cidx + rr2) & 15) * 8];
        *(h16x8*)&Out[(long)r * 128 + cidx * 8] = vv;
      }
    }
  }
}

// ================= pooling v2: wave-per-row 16B loads, LDS cross-wave reduce =================
__global__ __launch_bounds__(256) void pool_direct(
    const _Float16* __restrict__ H1, const _Float16* __restrict__ H2,
    const _Float16* __restrict__ H3, const int* __restrict__ gstart,
    float* __restrict__ P)
{
  __shared__ float red[3 * 16 * 8 * 4];   // [tbl][chunk][elt][wave] = 6 KB
  int g = blockIdx.x;
  int s = gstart[g], e = gstart[g + 1];
  int tid = threadIdx.x;
  int wv = tid >> 6, lane = tid & 63;
  int tbl = lane >> 4;
  int ch = lane & 15;
  float a[8];
#pragma unroll
  for (int j = 0; j < 8; ++j) a[j] = 0.f;
  if (tbl < 3) {
    const _Float16* A = (tbl == 0) ? H1 : ((tbl == 1) ? H2 : H3);
    const _Float16* Ac = A + ch * 8;
    for (int r = s + wv; r < e; r += 4) {
      h16x8 v = *(const h16x8*)&Ac[(long)r * 128];
#pragma unroll
      for (int j = 0; j < 8; ++j) a[j] += (float)v[j];
    }
#pragma unroll
    for (int j = 0; j < 8; ++j) red[((tbl * 16 + ch) * 8 + j) * 4 + wv] = a[j];
  }
  __syncthreads();
  for (int t = tid; t < 384; t += 256) {
    float4 rv = *(const float4*)&red[t * 4];
    P[(long)g * 384 + t] = rv.x + rv.y + rv.z + rv.w;
  }
}

// ======== fused head GEMM: zc = P @ Wc + cnt*bc + c1b, with BN stat atomics ========
__global__ __launch_bounds__(256) void jk_bn(
    const float* __restrict__ P, const int* __restrict__ gstart,
    const float* __restrict__ Wc, const float* __restrict__ bc,
    const float* __restrict__ c1b,
    float* __restrict__ zc, float* __restrict__ bnstat)
{
  __shared__ float pl[8 * 384];   // 12 KB
  __shared__ float red[512];
  int tid = threadIdx.x, blk = blockIdx.x;
  int r0 = blk * 8;
  for (int o = tid; o < 8 * 384; o += 256)
    pl[o] = P[(long)r0 * 384 + o];
  __syncthreads();
  int col = tid & 127, rg = tid >> 7;
  float acc[4];
  float b0 = bc[col], b1 = c1b[col];
#pragma unroll
  for (int i = 0; i < 4; ++i) {
    int row = r0 + rg + 2 * i;
    float cntv = (float)(gstart[row + 1] - gstart[row]);
    acc[i] = cntv * b0 + b1;
  }
#pragma unroll 4
  for (int k = 0; k < 384; ++k) {
    float w = Wc[k * 128 + col];
#pragma unroll
    for (int i = 0; i < 4; ++i)
      acc[i] += pl[(rg + 2 * i) * 384 + k] * w;
  }
  float s = 0.f, s2 = 0.f;
#pragma unroll
  for (int i = 0; i < 4; ++i) {
    int row = r0 + rg + 2 * i;
    zc[(long)row * 128 + col] = acc[i];
    s += acc[i]; s2 += acc[i] * acc[i];
  }
  red[tid] = s; red[256 + tid] = s2;
  __syncthreads();
  if (tid < 128) {
    atomicAdd(&bnstat[tid], red[tid] + red[tid + 128]);
    atomicAdd(&bnstat[128 + tid], red[256 + tid] + red[256 + tid + 128]);
  }
}

// ================= BN apply + relu + final [128x2] matmul (64 graphs/block) =================
__global__ __launch_bounds__(256) void bn_final(
    const float* __restrict__ ZC, const float* __restrict__ bnstat,
    const float* __restrict__ gma, const float* __restrict__ bta,
    const float* __restrict__ W2, const float* __restrict__ B2, float* __restrict__ out)
{
  __shared__ float scl[128], shf[128];
  __shared__ float zl[64 * 132];   // stride 132 -> conflict-free reads
  int tid = threadIdx.x;
  if (tid < 128) {
    float mu = bnstat[tid] * (1.f / NGRAPH);
    float var = bnstat[128 + tid] * (1.f / NGRAPH) - mu * mu;
    float rs = rsqrtf(var + 1e-5f);
    float sc = gma[tid] * rs;
    scl[tid] = sc;
    shf[tid] = bta[tid] - mu * sc;
  }
  int g0 = blockIdx.x * 64;
  for (int i = tid; i < 64 * 128; i += 256) {
    int r = i >> 7, c = i & 127;
    zl[r * 132 + c] = ZC[(long)(g0 + r) * 128 + c];
  }
  __syncthreads();
  int q = tid >> 2, sub = tid & 3;
  int g = g0 + q;
  float a0 = 0.f, a1 = 0.f;
#pragma unroll 8
  for (int hh = 0; hh < 32; ++hh) {
    int h = sub + hh * 4;
    float zn = zl[q * 132 + h] * scl[h] + shf[h];
    zn = fmaxf(zn, 0.f);
    a0 += zn * W2[2 * h];
    a1 += zn * W2[2 * h + 1];
  }
  a0 += __shfl_xor(a0, 1, 64); a0 += __shfl_xor(a0, 2, 64);
  a1 += __shfl_xor(a1, 1, 64); a1 += __shfl_xor(a1, 2, 64);
  if (sub == 0) {
    out[2 * g] = a0 + B2[0];
    out[2 * g + 1] = a1 + B2[1];
  }
}

extern "C" void kernel_launch(void* const* d_in, const int* in_sizes, int n_in,
                              void* d_out, int out_size, void* d_ws, size_t ws_size,
                              hipStream_t stream)
{
  const float* x    = (const float*)d_in[0];
  const int*   ei   = (const int*)d_in[1];
  const int*   batch = (const int*)d_in[3];
  const float* g1w1 = (const float*)d_in[4];  const float* g1b1 = (const float*)d_in[5];
  const float* g1w2 = (const float*)d_in[6];  const float* g1b2 = (const float*)d_in[7];
  const float* g2w1 = (const float*)d_in[8];  const float* g2b1 = (const float*)d_in[9];
  const float* g2w2 = (const float*)d_in[10]; const float* g2b2 = (const float*)d_in[11];
  const float* g3w1 = (const float*)d_in[12]; const float* g3b1 = (const float*)d_in[13];
  const float* g3w2 = (const float*)d_in[14]; const float* g3b2 = (const float*)d_in[15];
  const float* jkw  = (const float*)d_in[16]; const float* jkb  = (const float*)d_in[17];
  const float* c1w  = (const float*)d_in[18]; const float* c1b  = (const float*)d_in[19];
  const float* bng  = (const float*)d_in[20]; const float* bnb  = (const float*)d_in[21];
  const float* c2w  = (const float*)d_in[22]; const float* c2b  = (const float*)d_in[23];

  const int N = in_sizes[3];
  const int E = in_sizes[1] / 2;
  const int* src = ei;
  const int* dst = ei + E;

  char* w = (char*)d_ws;
  auto alloc = [&](size_t bytes) {
    char* p = w;
    w += (bytes + 255) & ~(size_t)255;
    return p;
  };
  _Float16* hA = (_Float16*)alloc((size_t)N * 128 * 2);   // layer-3 out
  _Float16* hB = (_Float16*)alloc((size_t)N * 128 * 2);   // layer-2 out
  _Float16* hC = (_Float16*)alloc((size_t)N * 128 * 2);   // layer-1 out
  _Float16* x8h = (_Float16*)alloc((size_t)N * 8 * 2);
  float* P       = (float*)alloc((size_t)NGRAPH * 384 * 4);
  float* bnstat  = (float*)alloc(256 * 4);
  float* zc   = (float*)alloc((size_t)NGRAPH * 128 * 4);
  float* wc   = (float*)alloc((size_t)384 * 128 * 4);
  float* bcv  = (float*)alloc((size_t)128 * 4);
  // deg, scanst contiguous -> one memset
  int* deg      = (int*)alloc((size_t)N * 4);
  unsigned* scanst = (unsigned*)alloc((size_t)1024 * 4);
  int* rank     = (int*)alloc((size_t)E * 4);
  int* rowstart = (int*)alloc((size_t)(N + 1) * 4);
  int* eidx     = (int*)alloc((size_t)E * 4);
  int* gstart   = (int*)alloc((size_t)(NGRAPH + 1) * 4);
  _Float16* wtbuf = (_Float16*)alloc((size_t)5 * 2 * 16384 * 2);

  _Float16* WThi[5];
  _Float16* WTlo[5];
  for (int m = 0; m < 5; ++m) {
    WThi[m] = wtbuf + (size_t)m * 2 * 16384;
    WTlo[m] = WThi[m] + 16384;
  }

  const int nchunk = (N + 255) / 256;
  const int eb = (E + 255) / 256;

  // ---- memset deg+scanst (contiguous allocs incl. padding) ----
  hipMemsetAsync(deg, 0, (size_t)((char*)(scanst + 1024) - (char*)deg), stream);

  // ---- merged hist(rank-capture) + weight prep + x pad + zero(bnstat) + bounds + Wc/bc ----
  {
    WPs p;
    p.w[0] = g1w2; p.w[1] = g2w1; p.w[2] = g2w2; p.w[3] = g3w1; p.w[4] = g3w2;
    for (int m = 0; m < 5; ++m) { p.hi[m] = WThi[m]; p.lo[m] = WTlo[m]; }
    int total = E + 5 * 16384 + N * 8 + 256 + N + 384 * 128 + 128;
    prep_hist<<<(total + 255) / 256, 256, 0, stream>>>(p, x, x8h, N, dst, deg, rank, E,
                                                       batch, gstart, bnstat,
                                                       jkw, jkb, c1w, wc, bcv);
  }

  // ---- scan (rowstart only) + atomic-free fill ----
  scan_onepass<<<nchunk, 256, 0, stream>>>(deg, rowstart, scanst, N, E, nchunk);
  fill_eidx<<<eb, 256, 0, stream>>>(src, dst, rank, rowstart, eidx, E);

  const int fBlocks = (N + 63) / 64;

  // ---- layers (re-fused; f16-MFMA weights) ----
  fused_l1<<<fBlocks, 256, 0, stream>>>(x8h, rowstart, eidx, g1w1, g1b1,
      WThi[0], WTlo[0], g1b2, hC, N);
  fused_gin<<<fBlocks, 256, 0, stream>>>(hC, rowstart, eidx,
      WThi[1], WTlo[1], g2b1, WThi[2], WTlo[2], g2b2, hB, N);
  fused_gin<<<fBlocks, 256, 0, stream>>>(hB, rowstart, eidx,
      WThi[3], WTlo[3], g3b1, WThi[4], WTlo[4], g3b2, hA, N);

  // ---- pooling v2: one block per graph, 16B loads, no atomics ----
  pool_direct<<<NGRAPH, 256, 0, stream>>>(hC, hB, hA, gstart, P);

  // ---- fused head: zc = P@Wc + cnt*bc + c1b (+BN stats), then BN+final ----
  jk_bn<<<NGRAPH / 8, 256, 0, stream>>>(P, gstart, wc, bcv, c1b, zc, bnstat);
  bn_final<<<NGRAPH / 64, 256, 0, stream>>>(zc, bnstat, bng, bnb, c2w, c2b, (float*)d_out);
}